// Round 7
// baseline (845.450 us; speedup 1.0000x reference)
//
#include <hip/hip_runtime.h>
#include <math.h>

#define B_ 4
#define H_ 32
#define KVH_ 8
#define D_ 128
#define HID_ 4096
#define S_CACHE_ 8191
#define W_ 512

// ws layout (float offsets)
#define OFF_QRAW   0        // 16384
#define OFF_KRAW   16384    // 4096
#define OFF_VNEW   20480    // 4096
#define OFF_QROPE  24576    // 16384
#define OFF_KROPE  40960    // 4096
#define OFF_TSP    45056    // 65536
#define OFF_SELCNT 110592   // 128 ints
#define OFF_SELLST 110720   // 10240 ints
#define OFF_PM     120960   // 512
#define OFF_PL     121472   // 512
#define OFF_PO     121984   // 65536
#define OFF_AO     187520   // 16384

typedef _Float16 half4v __attribute__((ext_vector_type(4)));
typedef _Float16 half8v __attribute__((ext_vector_type(8)));
typedef float f4v __attribute__((ext_vector_type(4)));

__global__ void k_init(float* __restrict__ ws, float* __restrict__ out) {
  int i = blockIdx.x * 256 + threadIdx.x;
  if (i < 24576) ws[i] = 0.f;        // q_raw, k_raw, v_new (atomicAdd targets)
  if (i < 16384) out[i] = 0.f;       // d_out (atomicAdd target)
}

// hidden (4,4096) @ [Wq|Wk|Wv], split 64-way over K rows, atomicAdd partials.
__global__ __launch_bounds__(256) void k_qkv(const float* __restrict__ hid,
                      const float* __restrict__ Wq,
                      const float* __restrict__ Wk,
                      const float* __restrict__ Wv,
                      float* __restrict__ ws) {
  __shared__ float hs[4][64];
  int cb = blockIdx.x % 6;       // 0..3: q cols, 4: k, 5: v
  int isp = blockIdx.x / 6;      // 0..63
  int r0 = isp * 64;
  int tid = threadIdx.x;
  hs[tid >> 6][tid & 63] = hid[(tid >> 6) * HID_ + r0 + (tid & 63)];
  __syncthreads();
  const float* Wm; int stride; float* dst; int jl; int span;
  if (cb < 4)      { Wm = Wq; stride = 4096; dst = ws + OFF_QRAW; jl = cb * 1024 + tid * 4; span = 4096; }
  else if (cb == 4){ Wm = Wk; stride = 1024; dst = ws + OFF_KRAW; jl = tid * 4; span = 1024; }
  else             { Wm = Wv; stride = 1024; dst = ws + OFF_VNEW; jl = tid * 4; span = 1024; }
  float acc[4][4];
  #pragma unroll
  for (int b = 0; b < 4; b++) { acc[b][0]=0.f; acc[b][1]=0.f; acc[b][2]=0.f; acc[b][3]=0.f; }
  const float* wp = Wm + (size_t)r0 * stride + jl;
  for (int ii = 0; ii < 64; ii++) {
    float4 w4 = *(const float4*)(wp);
    wp += stride;
    #pragma unroll
    for (int b = 0; b < 4; b++) {
      float hv = hs[b][ii];
      acc[b][0] += hv * w4.x; acc[b][1] += hv * w4.y;
      acc[b][2] += hv * w4.z; acc[b][3] += hv * w4.w;
    }
  }
  #pragma unroll
  for (int b = 0; b < 4; b++)
    #pragma unroll
    for (int t = 0; t < 4; t++)
      atomicAdd(&dst[b * span + jl + t], acc[b][t]);
}

// RoPE for q (32 heads) and k_new (8 heads)
__global__ void k_rope(const float* __restrict__ cosb, const float* __restrict__ sinb,
                       float* __restrict__ ws) {
  int idx = blockIdx.x * 256 + threadIdx.x;
  if (idx >= 4 * 40 * 64) return;
  int dp = idx & 63;
  int head = (idx >> 6) % 40;
  int b = idx / (40 * 64);
  const float* src; float* dstp;
  if (head < 32) { src = ws + OFF_QRAW + (b * 32 + head) * 128; dstp = ws + OFF_QROPE + (b * 32 + head) * 128; }
  else           { src = ws + OFF_KRAW + (b * 8 + head - 32) * 128; dstp = ws + OFF_KROPE + (b * 8 + head - 32) * 128; }
  float x0 = src[dp], x1 = src[dp + 64];
  float c0 = cosb[b * 128 + dp], c1 = cosb[b * 128 + dp + 64];
  float s0 = sinb[b * 128 + dp], s1 = sinb[b * 128 + dp + 64];
  dstp[dp]      = x0 * c0 - x1 * s0;
  dstp[dp + 64] = x1 * c1 + x0 * s1;
}

// Fused CNN with fp16-split MFMA conv2.
// Block = (image n, 64-col tile). conv1 (fp32 VALU) -> split fp16 hi/lo into 6-row LDS ring,
// layout [slot][col(66)][var(2)][c1(16)] fp16, col stride 40 elems (80B) for bank spread.
// conv2 as GEMM: D[c2(32)][pos(16/wave)] over K=144=(tap*16+c1); A (weights split) in regs;
// 3 passes (AhBh, AhBl, AlBh); K = 4x mfma_16x16x32_f16 + 1x mfma_16x16x16_f16.
// Epilogue per row: relu(acc+b2) accumulated into meanacc; final: dot c3, /64, lane-reduce.
__global__ __launch_bounds__(256) void k_cnn(const float* __restrict__ hist,
            const float* __restrict__ c1w, const float* __restrict__ c1b,
            const float* __restrict__ c2w, const float* __restrict__ c2b,
            const float* __restrict__ c3w, const float* __restrict__ c3b,
            float* __restrict__ ws) {
  __shared__ __align__(16) _Float16 r1s[6 * 2640];   // 6 slots * 66 cols * 40 elems
  __shared__ __align__(16) _Float16 Ah[32 * 168];    // [c2][k(144, pad 168)]
  __shared__ __align__(16) _Float16 Al[32 * 168];
  __shared__ float inr[4][68];                       // input ring, col0 = w0-2
  __shared__ float w1s[144];
  __shared__ float b1s[16];
  int n = blockIdx.x >> 3;
  int w0 = (blockIdx.x & 7) * 64;
  int tid = threadIdx.x;
  int lane = tid & 63, wid = tid >> 6;

  // ---- stage conv1 weights + conv2 weights (transposed k=tap*16+c1, fp16 split) ----
  for (int t = tid; t < 144; t += 256) w1s[t] = c1w[t];
  if (tid < 16) b1s[tid] = c1b[tid];
  for (int t = tid; t < 4608; t += 256) {
    int c2 = t / 144, rem = t - c2 * 144;
    int c1 = rem / 9, tap = rem - c1 * 9;
    float wv = c2w[t];
    _Float16 h = (_Float16)wv;
    _Float16 l = (_Float16)(wv - (float)h);
    int k = tap * 16 + c1;
    Ah[c2 * 168 + k] = h;
    Al[c2 * 168 + k] = l;
  }
  // ---- input rows 0..3 ----
  const float* src = hist + (size_t)n * (64 * 512);
  #pragma unroll
  for (int rr = 0; rr < 4; rr++) {
    if (tid < 68) {
      int gc = w0 - 2 + tid;
      inr[rr][tid] = (gc >= 0 && gc < 512) ? src[rr * 512 + gc] : 0.f;
    }
  }
  __syncthreads();

  // ---- A fragments to registers ----
  half8v Afh[2][4], Afl[2][4];
  half4v Afh4[2], Afl4[2];
  int g = (lane >> 4) & 3;
  #pragma unroll
  for (int mt = 0; mt < 2; mt++) {
    int c2r = mt * 16 + (lane & 15);
    #pragma unroll
    for (int s = 0; s < 4; s++) {
      int k = s * 32 + g * 8;
      Afh[mt][s] = *(const half8v*)&Ah[c2r * 168 + k];
      Afl[mt][s] = *(const half8v*)&Al[c2r * 168 + k];
    }
    int k4 = 128 + g * 4;
    Afh4[mt] = *(const half4v*)&Ah[c2r * 168 + k4];
    Afl4[mt] = *(const half4v*)&Al[c2r * 168 + k4];
  }
  // bias / c3 per-lane (c2 = mt*16 + g*4 + i)
  float b2v[2][4], c3v[2][4];
  #pragma unroll
  for (int mt = 0; mt < 2; mt++)
    #pragma unroll
    for (int i = 0; i < 4; i++) {
      b2v[mt][i] = c2b[mt * 16 + g * 4 + i];
      c3v[mt][i] = c3w[mt * 16 + g * 4 + i];
    }

  // ---- conv1 producer (row -> ring slot row%6), writes fp16 hi/lo ----
  auto produce = [&](int row) {
    int sl = ((row % 6) + 6) % 6;
    _Float16* base = &r1s[sl * 2640];
    for (int o = tid; o < 1056; o += 256) {
      int c1 = o / 66, wj = o - c1 * 66;
      float a = 0.f;
      int gcol = w0 - 1 + wj;
      if (row >= 0 && row < 64 && gcol >= 0 && gcol < 512) {
        a = b1s[c1];
        #pragma unroll
        for (int dh = 0; dh < 3; dh++) {
          int rr = row - 1 + dh;
          if (rr >= 0 && rr < 64) {
            const float* ir = inr[rr & 3];
            a += w1s[c1 * 9 + dh * 3 + 0] * ir[wj]
               + w1s[c1 * 9 + dh * 3 + 1] * ir[wj + 1]
               + w1s[c1 * 9 + dh * 3 + 2] * ir[wj + 2];
          }
        }
        a = fmaxf(a, 0.f);
      }
      _Float16 h = (_Float16)a;
      _Float16 l = (_Float16)(a - (float)h);
      base[wj * 40 + c1] = h;
      base[wj * 40 + 16 + c1] = l;
    }
  };
  auto loadin = [&](int row) {
    if (row >= 0 && row < 64 && tid < 68) {
      int gc = w0 - 2 + tid;
      inr[row & 3][tid] = (gc >= 0 && gc < 512) ? src[row * 512 + gc] : 0.f;
    }
  };

  produce(-1); produce(0); produce(1);
  __syncthreads();

  // ---- per-lane B-fragment offsets (elem units; col stride 40) ----
  int c0 = wid * 16 + (lane & 15);
  int hw = lane >> 5;
  int c1h8 = (g & 1) * 8;
  int off0 = (c0 + hw) * 40 + c1h8;                 // ksteps 0 & 3 (dw = hw)
  int off1 = (c0 + (hw ? 0 : 2)) * 40 + c1h8;       // kstep 1 (tap2 dw2 / tap3 dw0)
  int off2 = (c0 + 1 + hw) * 40 + c1h8;             // kstep 2 (dw = 1+hw)
  int off4 = (c0 + 2) * 40 + g * 4;                 // kstep 4 K16 (tap8 dw2)

  float macc[2][4];
  #pragma unroll
  for (int mt = 0; mt < 2; mt++)
    #pragma unroll
    for (int i = 0; i < 4; i++) macc[mt][i] = 0.f;

  for (int r = 0; r < 64; ++r) {
    // ---- consume row r: MFMA over K=144, N-tile = this wave's 16 cols ----
    int sbm = ((r + 5) % 6) * 2640;
    int sb0 = (r % 6) * 2640;
    int sbp = ((r + 1) % 6) * 2640;
    int sb1 = (lane < 32) ? sbm : sb0;   // kstep1: tap2 row r-1 | tap3 row r
    int sbs[4]  = {sbm, sb1, sb0, sbp};
    int offs[4] = {off0, off1, off2, off0};
    f4v a0 = {0.f, 0.f, 0.f, 0.f};
    f4v a1 = {0.f, 0.f, 0.f, 0.f};
    #pragma unroll
    for (int s = 0; s < 4; s++) {
      half8v bh = *(const half8v*)&r1s[sbs[s] + offs[s]];
      half8v bl = *(const half8v*)&r1s[sbs[s] + offs[s] + 16];
      a0 = __builtin_amdgcn_mfma_f32_16x16x32_f16(Afh[0][s], bh, a0, 0, 0, 0);
      a1 = __builtin_amdgcn_mfma_f32_16x16x32_f16(Afh[1][s], bh, a1, 0, 0, 0);
      a0 = __builtin_amdgcn_mfma_f32_16x16x32_f16(Afh[0][s], bl, a0, 0, 0, 0);
      a1 = __builtin_amdgcn_mfma_f32_16x16x32_f16(Afh[1][s], bl, a1, 0, 0, 0);
      a0 = __builtin_amdgcn_mfma_f32_16x16x32_f16(Afl[0][s], bh, a0, 0, 0, 0);
      a1 = __builtin_amdgcn_mfma_f32_16x16x32_f16(Afl[1][s], bh, a1, 0, 0, 0);
    }
    {
      half4v bh = *(const half4v*)&r1s[sbp + off4];
      half4v bl = *(const half4v*)&r1s[sbp + off4 + 16];
      a0 = __builtin_amdgcn_mfma_f32_16x16x16f16(Afh4[0], bh, a0, 0, 0, 0);
      a1 = __builtin_amdgcn_mfma_f32_16x16x16f16(Afh4[1], bh, a1, 0, 0, 0);
      a0 = __builtin_amdgcn_mfma_f32_16x16x16f16(Afh4[0], bl, a0, 0, 0, 0);
      a1 = __builtin_amdgcn_mfma_f32_16x16x16f16(Afh4[1], bl, a1, 0, 0, 0);
      a0 = __builtin_amdgcn_mfma_f32_16x16x16f16(Afl4[0], bh, a0, 0, 0, 0);
      a1 = __builtin_amdgcn_mfma_f32_16x16x16f16(Afl4[1], bh, a1, 0, 0, 0);
    }
    #pragma unroll
    for (int i = 0; i < 4; i++) {
      macc[0][i] += fmaxf(a0[i] + b2v[0][i], 0.f);
      macc[1][i] += fmaxf(a1[i] + b2v[1][i], 0.f);
    }
    // ---- produce row r+2, load input row r+4 ----
    produce(r + 2);
    loadin(r + 4);
    __syncthreads();
  }

  float part = 0.f;
  #pragma unroll
  for (int i = 0; i < 4; i++)
    part += c3v[0][i] * macc[0][i] + c3v[1][i] * macc[1][i];
  part *= (1.f / 64.f);
  part += __shfl_xor(part, 16);
  part += __shfl_xor(part, 32);
  if (lane < 16)
    ws[OFF_TSP + n * 512 + w0 + wid * 16 + lane] = part + c3b[0];
}

// exact top-64 per (b,h) by rank counting (jax tie-break: lower index wins), union sink/local blocks
__global__ void k_topk(float* __restrict__ ws) {
  __shared__ float sv[512];
  __shared__ int cnt_s;
  __shared__ int list_s[80];
  int n = blockIdx.x;
  int tid = threadIdx.x;
  const float* tsp = ws + OFF_TSP + n * 512;
  for (int t = tid; t < 512; t += 256) sv[t] = tsp[t];
  if (tid == 0) cnt_s = 0;
  __syncthreads();
  for (int i = tid; i < 512; i += 256) {
    float vi = sv[i];
    int c = 0;
    for (int j = 0; j < 512; j++) {
      float vj = sv[j];
      c += (vj > vi) || (vj == vi && j < i);
    }
    if (c < 64 || i < 4 || i >= 508) {
      int pos = atomicAdd(&cnt_s, 1);
      list_s[pos] = i;
    }
  }
  __syncthreads();
  int* cl = (int*)(ws + OFF_SELCNT);
  int* ll = (int*)(ws + OFF_SELLST);
  if (tid == 0) cl[n] = cnt_s;
  for (int t = tid; t < cnt_s; t += 256) ll[n * 80 + t] = list_s[t];
}

__device__ inline float wred_max(float v) {
  #pragma unroll
  for (int o = 32; o > 0; o >>= 1) v = fmaxf(v, __shfl_down(v, o));
  return v;
}
__device__ inline float wred_sum(float v) {
  #pragma unroll
  for (int o = 32; o > 0; o >>= 1) v += __shfl_down(v, o);
  return v;
}

// sparse attention, 4 split-blocks per (b,h); online-softmax partials (m, l, o) to ws
__global__ __launch_bounds__(256) void k_attn(const float* __restrict__ kc,
                       const float* __restrict__ vc,
                       float* __restrict__ ws) {
  __shared__ float q_s[128];
  __shared__ float sc_s[288];
  __shared__ float red_s[4];
  __shared__ float bc_s;
  __shared__ float o_s[2][128];
  int bid = blockIdx.x;
  int bh = bid >> 2, sp = bid & 3;
  int b = bh >> 5, h = bh & 31, kvh = h >> 2;
  int tid = threadIdx.x;
  const int* cl = (const int*)(ws + OFF_SELCNT);
  const int* ll = (const int*)(ws + OFF_SELLST) + bh * 80;
  int nsel = cl[bh];
  int nloc = (nsel > sp) ? ((nsel - sp + 3) >> 2) : 0;
  int ntok = nloc * 16;
  if (tid < 128) q_s[tid] = ws[OFF_QROPE + bh * 128 + tid];
  __syncthreads();
  const float* kbase = kc + (size_t)(b * 8 + kvh) * S_CACHE_ * 128;
  const float* knew = ws + OFF_KROPE + (b * 8 + kvh) * 128;
  for (int slot = tid; slot < ntok; slot += 256) {
    int lb = slot >> 4, jt = slot & 15;
    int blk = ll[sp + 4 * lb];
    int gg = blk * 16 + jt;
    const float* kr = (gg < S_CACHE_) ? (kbase + (size_t)gg * 128) : knew;
    float s = 0.f;
    #pragma unroll 8
    for (int d = 0; d < 128; d += 4) {
      float4 k4 = *(const float4*)(kr + d);
      s += q_s[d] * k4.x + q_s[d + 1] * k4.y + q_s[d + 2] * k4.z + q_s[d + 3] * k4.w;
    }
    sc_s[slot] = s * 0.08838834764831845f;   // 1/sqrt(128)
  }
  __syncthreads();
  float m = -1e30f;
  for (int slot = tid; slot < ntok; slot += 256) m = fmaxf(m, sc_s[slot]);
  m = wred_max(m);
  int lane = tid & 63, wid = tid >> 6;
  if (lane == 0) red_s[wid] = m;
  __syncthreads();
  if (tid == 0) bc_s = fmaxf(fmaxf(red_s[0], red_s[1]), fmaxf(red_s[2], red_s[3]));
  __syncthreads();
  float M = bc_s;
  float l = 0.f;
  for (int slot = tid; slot < ntok; slot += 256) {
    float p = __expf(sc_s[slot] - M);
    sc_s[slot] = p;
    l += p;
  }
  l = wred_sum(l);
  __syncthreads();
  if (lane == 0) red_s[wid] = l;
  __syncthreads();
  float L = red_s[0] + red_s[1] + red_s[2] + red_s[3];
  // PV
  int d = tid & 127, ch = tid >> 7;
  const float* vbase = vc + (size_t)(b * 8 + kvh) * S_CACHE_ * 128;
  const float* vnew = ws + OFF_VNEW + (b * 8 + kvh) * 128;
  float acc = 0.f;
  for (int slot = ch; slot < ntok; slot += 2) {
    int lb = slot >> 4, jt = slot & 15;
    int blk = ll[sp + 4 * lb];
    int gg = blk * 16 + jt;
    const float* vr = (gg < S_CACHE_) ? (vbase + (size_t)gg * 128) : vnew;
    acc += sc_s[slot] * vr[d];
  }
  o_s[ch][d] = acc;
  __syncthreads();
  if (tid == 0) { ws[OFF_PM + bid] = M; ws[OFF_PL + bid] = L; }
  if (tid < 128) ws[OFF_PO + (size_t)bid * 128 + tid] = o_s[0][tid] + o_s[1][tid];
}

__global__ void k_comb(float* __restrict__ ws) {
  int bh = blockIdx.x, d = threadIdx.x;  // 128 threads
  float m0 = ws[OFF_PM + bh * 4 + 0], m1 = ws[OFF_PM + bh * 4 + 1];
  float m2 = ws[OFF_PM + bh * 4 + 2], m3 = ws[OFF_PM + bh * 4 + 3];
  float M = fmaxf(fmaxf(m0, m1), fmaxf(m2, m3));
  float e0 = __expf(m0 - M), e1 = __expf(m1 - M), e2 = __expf(m2 - M), e3 = __expf(m3 - M);
  float L = e0 * ws[OFF_PL + bh * 4 + 0] + e1 * ws[OFF_PL + bh * 4 + 1]
          + e2 * ws[OFF_PL + bh * 4 + 2] + e3 * ws[OFF_PL + bh * 4 + 3];
  float O = e0 * ws[OFF_PO + (size_t)(bh * 4 + 0) * 128 + d]
          + e1 * ws[OFF_PO + (size_t)(bh * 4 + 1) * 128 + d]
          + e2 * ws[OFF_PO + (size_t)(bh * 4 + 2) * 128 + d]
          + e3 * ws[OFF_PO + (size_t)(bh * 4 + 3) * 128 + d];
  ws[OFF_AO + bh * 128 + d] = O / L;
}

// attn_out (4,4096) @ Wo (4096,4096), split 64-way over K, atomicAdd into zeroed d_out
__global__ __launch_bounds__(256) void k_oproj(const float* __restrict__ Wo,
                        const float* __restrict__ ws, float* __restrict__ out) {
  __shared__ float as[4][64];
  int cb = blockIdx.x % 4, isp = blockIdx.x / 4;
  int r0 = isp * 64, tid = threadIdx.x;
  as[tid >> 6][tid & 63] = ws[OFF_AO + (tid >> 6) * 4096 + r0 + (tid & 63)];
  __syncthreads();
  int jl = cb * 1024 + tid * 4;
  float acc[4][4];
  #pragma unroll
  for (int b = 0; b < 4; b++) { acc[b][0]=0.f; acc[b][1]=0.f; acc[b][2]=0.f; acc[b][3]=0.f; }
  const float* wp = Wo + (size_t)r0 * 4096 + jl;
  for (int ii = 0; ii < 64; ii++) {
    float4 w4 = *(const float4*)(wp);
    wp += 4096;
    #pragma unroll
    for (int b = 0; b < 4; b++) {
      float hv = as[b][ii];
      acc[b][0] += hv * w4.x; acc[b][1] += hv * w4.y;
      acc[b][2] += hv * w4.z; acc[b][3] += hv * w4.w;
    }
  }
  #pragma unroll
  for (int b = 0; b < 4; b++)
    #pragma unroll
    for (int t = 0; t < 4; t++)
      atomicAdd(&out[b * 4096 + jl + t], acc[b][t]);
}

extern "C" void kernel_launch(void* const* d_in, const int* in_sizes, int n_in,
                              void* d_out, int out_size, void* d_ws, size_t ws_size,
                              hipStream_t stream) {
  const float* hid  = (const float*)d_in[0];
  const float* kc   = (const float*)d_in[1];
  const float* vc   = (const float*)d_in[2];
  const float* hist = (const float*)d_in[3];
  const float* cosb = (const float*)d_in[4];
  const float* sinb = (const float*)d_in[5];
  const float* Wq   = (const float*)d_in[6];
  const float* Wk   = (const float*)d_in[7];
  const float* Wv   = (const float*)d_in[8];
  const float* Wo   = (const float*)d_in[9];
  const float* c1w  = (const float*)d_in[10];
  const float* c1b  = (const float*)d_in[11];
  const float* c2w  = (const float*)d_in[12];
  const float* c2b  = (const float*)d_in[13];
  const float* c3w  = (const float*)d_in[14];
  const float* c3b  = (const float*)d_in[15];
  float* ws = (float*)d_ws;
  float* out = (float*)d_out;

  hipLaunchKernelGGL(k_init,  dim3(96),   dim3(256), 0, stream, ws, out);
  hipLaunchKernelGGL(k_qkv,   dim3(384),  dim3(256), 0, stream, hid, Wq, Wk, Wv, ws);
  hipLaunchKernelGGL(k_rope,  dim3(40),   dim3(256), 0, stream, cosb, sinb, ws);
  hipLaunchKernelGGL(k_cnn,   dim3(1024), dim3(256), 0, stream, hist, c1w, c1b, c2w, c2b, c3w, c3b, ws);
  hipLaunchKernelGGL(k_topk,  dim3(128),  dim3(256), 0, stream, ws);
  hipLaunchKernelGGL(k_attn,  dim3(512),  dim3(256), 0, stream, kc, vc, ws);
  hipLaunchKernelGGL(k_comb,  dim3(128),  dim3(128), 0, stream, ws);
  hipLaunchKernelGGL(k_oproj, dim3(256),  dim3(256), 0, stream, Wo, ws, out);
}